// Round 11
// baseline (671.937 us; speedup 1.0000x reference)
//
#include <hip/hip_runtime.h>
#include <hip/hip_bf16.h>

// MultiHeadAttention: B=2, S=2048, H=16, D=64, E=1024. f32 I/O, bf16 internal.
// R11 vs R10 (202us across 4 dispatches; per-kernel sum ~158us -> ~40us of
// inter-dispatch gap/cold-start):
//  * ONE persistent kernel, 768 blocks == exactly 3/CU (launch_bounds(256,3)
//    caps VGPR<=170, LDS 36.9KB*3=111KB<160KB -> all blocks co-resident by
//    construction; no cooperative API). Device-scope atomic barriers between
//    phases (G16 pattern: threadfence + release add / acquire spin).
//  * phases: prep(3072 items) / qkv(768 tiles) / attn(1024 tiles via dynamic
//    LPT work queue -- perfect balance) / out(512 tiles). Bodies = R10.
//  * barrier counters + attn queue live in d_out[0..15] (memset 64B, then
//    overwritten by phase 3's own output after the last barrier).

typedef __hip_bfloat16 bf16;
typedef __attribute__((ext_vector_type(8))) short bfrag;    // 8 bf16 = 4 VGPRs
typedef __attribute__((ext_vector_type(4))) float f32x4;
typedef __attribute__((ext_vector_type(16))) float f32x16;  // 32x32 C/D
typedef __attribute__((ext_vector_type(4))) short short4v;

#define MFMA16(a, b, c) __builtin_amdgcn_mfma_f32_16x16x32_bf16(a, b, c, 0, 0, 0)
#define MFMA32(a, b, c) __builtin_amdgcn_mfma_f32_32x32x16_bf16(a, b, c, 0, 0, 0)

__device__ __forceinline__ unsigned pkbf(float a, float b) {
  union { bf16 h[2]; unsigned u; } w;
  w.h[0] = __float2bfloat16(a);
  w.h[1] = __float2bfloat16(b);
  return w.u;
}

// device-scope grid barrier: all 768 blocks are co-resident by construction.
__device__ __forceinline__ void gbar(unsigned* c, unsigned target) {
  __syncthreads();
  if (threadIdx.x == 0) {
    __threadfence();   // agent release: drain + L2 writeback (multi-XCD)
    __hip_atomic_fetch_add(c, 1u, __ATOMIC_RELEASE, __HIP_MEMORY_SCOPE_AGENT);
    while (__hip_atomic_load(c, __ATOMIC_ACQUIRE, __HIP_MEMORY_SCOPE_AGENT) < target)
      __builtin_amdgcn_s_sleep(32);
    __threadfence();   // agent acquire: invalidate caches
  }
  __syncthreads();
}

__global__ __launch_bounds__(256, 3) void mha_fused(
    const float* __restrict__ x,
    const float* __restrict__ Wq, const float* __restrict__ bq,
    const float* __restrict__ Wk, const float* __restrict__ bk,
    const float* __restrict__ Wv, const float* __restrict__ bv,
    const float* __restrict__ Wo,
    bf16* __restrict__ WqkvT, bf16* __restrict__ WoT,
    bf16* __restrict__ Q, bf16* __restrict__ K_, bf16* __restrict__ Vt,
    bf16* __restrict__ O, bf16* __restrict__ xb,
    float* __restrict__ out, unsigned* cnt) {
  __shared__ __align__(16) char SH[36880];
  int id = blockIdx.x, t = threadIdx.x;

  // ================= phase 0: prep (weights transpose + x cast) ==========
  {
    bf16(*tile)[80] = (bf16(*)[80])SH;
    for (int item = id; item < 3072; item += 768) {
      if (item < 1024) {
        const float* src;
        bf16* dst;
        int srcld, dstld, r0, c0;
        if (item < 768) {
          int w = item >> 8, h = (item >> 4) & 15;
          r0 = (item & 15) * 64; c0 = 0;
          src = ((w == 0) ? Wq : (w == 1) ? Wk : Wv) + (long)h * 1024 * 64;
          dst = WqkvT + ((long)w * 1024 + h * 64) * 1024;
          srcld = 64; dstld = 1024;
        } else {
          int j = item - 768;
          c0 = (j & 15) * 64; r0 = (j >> 4) * 64;
          src = Wo; dst = WoT;
          srcld = 1024; dstld = 1024;
        }
        int lr = t >> 3, lc = (t & 7) << 3;
        __syncthreads();   // protect tile reuse across loop iterations
#pragma unroll
        for (int p = 0; p < 2; ++p) {
          int r = lr + p * 32;
          const float* s = src + (long)(r0 + r) * srcld + c0 + lc;
          union { bf16 h8[8]; bfrag v; } tmp;
#pragma unroll
          for (int j = 0; j < 8; ++j) tmp.h8[j] = __float2bfloat16(s[j]);
          *(bfrag*)(&tile[r][lc]) = tmp.v;
        }
        __syncthreads();
#pragma unroll
        for (int p = 0; p < 2; ++p) {
          int c = lr + p * 32;
          union { bf16 h8[8]; bfrag v; } tmp;
#pragma unroll
          for (int j = 0; j < 8; ++j) tmp.h8[j] = tile[lc + j][c];
          *(bfrag*)(dst + (long)(c0 + c) * dstld + r0 + lc) = tmp.v;
        }
      } else {
        long i = (long)(item - 1024) * 2048 + t * 8;
        float4 a = *(const float4*)(x + i);
        float4 b = *(const float4*)(x + i + 4);
        union { bf16 h[8]; bfrag v; } tmp;
        tmp.h[0] = __float2bfloat16(a.x); tmp.h[1] = __float2bfloat16(a.y);
        tmp.h[2] = __float2bfloat16(a.z); tmp.h[3] = __float2bfloat16(a.w);
        tmp.h[4] = __float2bfloat16(b.x); tmp.h[5] = __float2bfloat16(b.y);
        tmp.h[6] = __float2bfloat16(b.z); tmp.h[7] = __float2bfloat16(b.w);
        *(bfrag*)(xb + i) = tmp.v;
      }
    }
  }
  gbar(cnt + 0, 768);

  // ================= phase 1: fused QKV GEMM (768 tiles, 1:1) ============
  {
    const int K = 1024;
    bf16(*As)[72] = (bf16(*)[72])SH;             // 128*72*2 = 18432
    bf16(*Bs)[72] = (bf16(*)[72])(SH + 18432);   // 18432
    int xcd = id & 7, sw = id >> 3;
    int m0 = ((xcd << 2) | (sw & 3)) * 128;
    int n0 = (sw >> 2) * 128;
    int wave = t >> 6, lane = t & 63, quad = lane >> 4, col = lane & 15;
    int wr = (wave >> 1) * 64, wc = (wave & 1) * 64;
    f32x4 acc[4][4] = {};

    int srow = t >> 1, scol = (t & 1) * 32;
    const bf16* Ag = xb + (long)(m0 + srow) * K + scol;
    const bf16* Bg = WqkvT + (long)(n0 + srow) * K + scol;

    bfrag A0[4], B0[4], A1[4], B1[4];
#pragma unroll
    for (int i = 0; i < 4; ++i) {
      A0[i] = *(const bfrag*)(Ag + 8 * i);
      B0[i] = *(const bfrag*)(Bg + 8 * i);
      A1[i] = *(const bfrag*)(Ag + 64 + 8 * i);
      B1[i] = *(const bfrag*)(Bg + 64 + 8 * i);
    }

    for (int k0 = 0; k0 < K; k0 += 64) {
      __syncthreads();
#pragma unroll
      for (int i = 0; i < 4; ++i) {
        *(bfrag*)(&As[srow][scol + 8 * i]) = A0[i];
        *(bfrag*)(&Bs[srow][scol + 8 * i]) = B0[i];
      }
      int kn = (k0 + 128 < K) ? k0 + 128 : K - 64;
#pragma unroll
      for (int i = 0; i < 4; ++i) {
        A0[i] = A1[i]; B0[i] = B1[i];
        A1[i] = *(const bfrag*)(Ag + kn + 8 * i);
        B1[i] = *(const bfrag*)(Bg + kn + 8 * i);
      }
      __syncthreads();
#pragma unroll
      for (int kc = 0; kc < 2; ++kc) {
        bfrag ra[4], rb[4];
#pragma unroll
        for (int i = 0; i < 4; ++i)
          ra[i] = *(const bfrag*)(&As[wr + 16 * i + col][kc * 32 + quad * 8]);
#pragma unroll
        for (int c = 0; c < 4; ++c)
          rb[c] = *(const bfrag*)(&Bs[wc + 16 * c + col][kc * 32 + quad * 8]);
#pragma unroll
        for (int c = 0; c < 4; ++c)
#pragma unroll
          for (int i = 0; i < 4; ++i) acc[c][i] = MFMA16(ra[i], rb[c], acc[c][i]);
      }
    }

    int sel = n0 >> 10;   // 0=Q, 1=K, 2=V
    const float* bias = (sel == 0) ? bq : (sel == 1) ? bk : bv;
#pragma unroll
    for (int c = 0; c < 4; ++c) {
      int nn = (n0 + wc + 16 * c + col) & 1023;
      float bvv = bias[nn];
      int h = nn >> 6, d = nn & 63;
#pragma unroll
      for (int i = 0; i < 4; ++i) {
        int mb = m0 + wr + 16 * i + quad * 4;
        int b = mb >> 11, s0 = mb & 2047;
        if (sel < 2) {
          bf16* dst = (sel == 0) ? Q : K_;
          long base = ((long)((b << 4) + h) * 2048 + s0) * 64 + d;
#pragma unroll
          for (int r = 0; r < 4; ++r)
            dst[base + (long)r * 64] = __float2bfloat16(acc[c][i][r] + bvv);
        } else {
          union { bf16 h4[4]; short4v v; } pk;
#pragma unroll
          for (int r = 0; r < 4; ++r) pk.h4[r] = __float2bfloat16(acc[c][i][r] + bvv);
          *(short4v*)(Vt + (long)(((b << 4) + h) * 64 + d) * 2048 + s0) = pk.v;
        }
      }
    }
  }
  gbar(cnt + 1, 768);

  // ================= phase 2: attention (1024 tiles, dynamic LPT queue) ==
  {
    bf16(*Ks)[72] = (bf16(*)[72])SH;             // [128][72]
    bf16(*Vs)[136] = (bf16(*)[136])(SH + 18432); // [64][136]
    int* wslot = (int*)(SH + 36864);
    int wave = t >> 6, lane = t & 63;
    int qh = wave >> 1, jh = wave & 1, hi = lane >> 5, l5 = lane & 31;
    const float SC2 = 0.18033688f;   // (1/8)*log2(e); p = exp2(s*SC2 - 16)
    int krow = t >> 3, kg = (t & 7) * 8;
    int vrow = t >> 4, vg = (t & 15) * 8;

    for (;;) {
      __syncthreads();   // protect wslot + prior item's LDS reads
      if (t == 0)
        *wslot = (int)__hip_atomic_fetch_add(cnt + 3, 1u, __ATOMIC_RELAXED,
                                             __HIP_MEMORY_SCOPE_AGENT);
      __syncthreads();
      int item = *wslot;
      if (item >= 1024) break;

      int xcd = item & 7, jj = item >> 3;
      int qt = 31 - (jj >> 2);     // LPT: big tiles popped first
      int bh = ((jj & 3) << 3) | xcd;

      const bf16* Kbase = K_ + ((long)bh * 2048 + krow) * 64 + kg;
      const bf16* Vbase = Vt + ((long)bh * 64 + vrow) * 2048 + vg;
      int q0 = qt * 64;
      int nj = (qt >> 1) + 1;
      int qi = q0 + 32 * qh + l5;

      bfrag qa[4];
      const bf16* qp = Q + ((long)bh * 2048 + q0 + 32 * qh + l5) * 64 + hi * 8;
#pragma unroll
      for (int kd = 0; kd < 4; ++kd) qa[kd] = *(const bfrag*)(qp + kd * 16);

      f32x16 o0, o1;
      float lsum = 0.f;
#pragma unroll
      for (int r = 0; r < 16; ++r) { o0[r] = 0.f; o1[r] = 0.f; }

      bfrag kreg[4], vreg[4];
#pragma unroll
      for (int i = 0; i < 4; ++i)
        kreg[i] = *(const bfrag*)(Kbase + (long)(32 * i) * 64);

      for (int jt = 0; jt < nj; ++jt) {
        int j0 = jt * 128;
        __syncthreads();
#pragma unroll
        for (int i = 0; i < 4; ++i)
          *(bfrag*)(&Ks[krow + 32 * i][kg]) = kreg[i];
        int jn = (jt + 1 < nj) ? (jt + 1) * 128 : jt * 128;
#pragma unroll
        for (int i = 0; i < 4; ++i)
          vreg[i] = *(const bfrag*)(Vbase + (long)(16 * i) * 2048 + j0);
#pragma unroll
        for (int i = 0; i < 4; ++i)
          kreg[i] = *(const bfrag*)(Kbase + (long)(jn + 32 * i) * 64);
        __syncthreads();

        f32x16 s0, s1;
#pragma unroll
        for (int r = 0; r < 16; ++r) { s0[r] = 0.f; s1[r] = 0.f; }
#pragma unroll
        for (int kd = 0; kd < 4; ++kd) {
          bfrag ka0 = *(const bfrag*)(&Ks[jh * 64 + l5][kd * 16 + hi * 8]);
          bfrag ka1 = *(const bfrag*)(&Ks[jh * 64 + 32 + l5][kd * 16 + hi * 8]);
          s0 = MFMA32(ka0, qa[kd], s0);
          s1 = MFMA32(ka1, qa[kd], s1);
        }

        bool lastT = (jt == nj - 1);
        unsigned g[2][4][2];
#pragma unroll
        for (int jb = 0; jb < 2; ++jb) {
          float pv[16];
#pragma unroll
          for (int r = 0; r < 16; ++r) {
            int jl = (r & 3) + 8 * (r >> 2) + 4 * hi;
            int j = j0 + jh * 64 + jb * 32 + jl;
            float sv = jb ? s1[r] : s0[r];
            float p = __builtin_amdgcn_exp2f(fmaf(sv, SC2, -16.0f));
            if (lastT) p = (j <= qi) ? p : 0.f;
            lsum += p;
            pv[r] = p;
          }
#pragma unroll
          for (int gg = 0; gg < 4; ++gg) {
            g[jb][gg][0] = pkbf(pv[4 * gg], pv[4 * gg + 1]);
            g[jb][gg][1] = pkbf(pv[4 * gg + 2], pv[4 * gg + 3]);
          }
        }
#pragma unroll
        for (int i = 0; i < 4; ++i)
          *(bfrag*)(&Vs[vrow + 16 * i][vg]) = vreg[i];
        __syncthreads();

#pragma unroll
        for (int jb = 0; jb < 2; ++jb) {
#pragma unroll
          for (int c = 0; c < 2; ++c) {
            unsigned a0 = g[jb][2 * c][0], a1 = g[jb][2 * c][1];
            unsigned b0 = g[jb][2 * c + 1][0], b1 = g[jb][2 * c + 1][1];
            unsigned sa0 = __shfl_xor((int)a0, 32, 64);
            unsigned sa1 = __shfl_xor((int)a1, 32, 64);
            unsigned sb0 = __shfl_xor((int)b0, 32, 64);
            unsigned sb1 = __shfl_xor((int)b1, 32, 64);
            union { unsigned u[4]; bfrag f; } pf;
            pf.u[0] = hi ? sb0 : a0;
            pf.u[1] = hi ? sb1 : a1;
            pf.u[2] = hi ? b0 : sa0;
            pf.u[3] = hi ? b1 : sa1;
            int kk = jh * 64 + jb * 32 + c * 16 + hi * 8;
            bfrag av0 = *(const bfrag*)(&Vs[l5][kk]);
            bfrag av1 = *(const bfrag*)(&Vs[32 + l5][kk]);
            o0 = MFMA32(av0, pf.f, o0);
            o1 = MFMA32(av1, pf.f, o1);
          }
        }
      }

      lsum += __shfl_xor(lsum, 32, 64);

      __syncthreads();
      float* Osc = (float*)&Ks[0][0];              // [64 q][68 d]
      float* Lsc = (float*)&Vs[0][0];              // [64 q]
      bf16* Of = (bf16*)((char*)&Vs[0][0] + 512);  // [64 q][72 d]
      int q = 32 * qh + l5;
      if (jh == 1) {
#pragma unroll
        for (int r = 0; r < 16; ++r) {
          int d = (r & 3) + 8 * (r >> 2) + 4 * hi;
          Osc[q * 68 + d] = o0[r];
          Osc[q * 68 + 32 + d] = o1[r];
        }
        if (hi == 0) Lsc[q] = lsum;
      }
      __syncthreads();
      if (jh == 0) {
        float inv = 1.f / (lsum + Lsc[q]);
#pragma unroll
        for (int r = 0; r < 16; ++r) {
          int d = (r & 3) + 8 * (r >> 2) + 4 * hi;
          Of[q * 72 + d] = __float2bfloat16((o0[r] + Osc[q * 68 + d]) * inv);
          Of[q * 72 + 32 + d] = __float2bfloat16((o1[r] + Osc[q * 68 + 32 + d]) * inv);
        }
      }
      __syncthreads();
      int row = t >> 2, off = (t & 3) * 16;
      bf16* po = O + ((long)bh * 2048 + q0 + row) * 64 + off;
      *(bfrag*)(po) = *(const bfrag*)(&Of[row * 72 + off]);
      *(bfrag*)(po + 8) = *(const bfrag*)(&Of[row * 72 + off + 8]);
    }
  }
  gbar(cnt + 2, 768);

  // ================= phase 3: out projection (512 tiles) =================
  if (id < 512) {
    const int K = 1024;
    bf16(*As)[72] = (bf16(*)[72])SH;             // [128][72]
    bf16(*Bs)[72] = (bf16(*)[72])(SH + 18432);   // [64][72]
    int xcd = id & 7, sw = id >> 3;
    int m0 = ((xcd << 2) | (sw & 3)) * 128;
    int n0 = (sw >> 2) * 64;
    int wave = t >> 6, lane = t & 63, quad = lane >> 4, col = lane & 15;
    int wr = (wave >> 1) * 64, wc = (wave & 1) * 32;
    f32x4 acc[2][4] = {};

    int srA = t >> 1, scA = (t & 1) * 32;
    int srB = t >> 2, scB = (t & 3) * 16;
    int mrow = m0 + srA;
    int ob = mrow >> 11, os = mrow & 2047;
    const bf16* Ag = O + (long)ob * 2097152 + (long)os * 64 + scA;
    const bf16* Bg = WoT + (long)(n0 + srB) * K + scB;

    bfrag A0[4], A1[4];
    bfrag B0[2], B1[2];
#pragma unroll
    for (int i = 0; i < 4; ++i) {
      A0[i] = *(const bfrag*)(Ag + 8 * i);
      A1[i] = *(const bfrag*)(Ag + (long)64 * 2048 + 8 * i);
    }
#pragma unroll
    for (int i = 0; i < 2; ++i) {
      B0[i] = *(const bfrag*)(Bg + 8 * i);
      B1[i] = *(const bfrag*)(Bg + 64 + 8 * i);
    }

    for (int k0 = 0; k0 < K; k0 += 64) {
      __syncthreads();
#pragma unroll
      for (int i = 0; i < 4; ++i) *(bfrag*)(&As[srA][scA + 8 * i]) = A0[i];
#pragma unroll
      for (int i = 0; i < 2; ++i) *(bfrag*)(&Bs[srB][scB + 8 * i]) = B0[i];
      int kn = (k0 + 128 < K) ? k0 + 128 : K - 64;
#pragma unroll
      for (int i = 0; i < 4; ++i) {
        A0[i] = A1[i];
        A1[i] = *(const bfrag*)(Ag + (long)kn * 2048 + 8 * i);
      }
#pragma unroll
      for (int i = 0; i < 2; ++i) {
        B0[i] = B1[i];
        B1[i] = *(const bfrag*)(Bg + kn + 8 * i);
      }
      __syncthreads();
#pragma unroll
      for (int kc = 0; kc < 2; ++kc) {
        bfrag ra[4], rb[2];
#pragma unroll
        for (int i = 0; i < 4; ++i)
          ra[i] = *(const bfrag*)(&As[wr + 16 * i + col][kc * 32 + quad * 8]);
#pragma unroll
        for (int c = 0; c < 2; ++c)
          rb[c] = *(const bfrag*)(&Bs[wc + 16 * c + col][kc * 32 + quad * 8]);
#pragma unroll
        for (int c = 0; c < 2; ++c)
#pragma unroll
          for (int i = 0; i < 4; ++i) acc[c][i] = MFMA16(ra[i], rb[c], acc[c][i]);
      }
    }

#pragma unroll
    for (int c = 0; c < 2; ++c) {
      int n = n0 + wc + 16 * c + col;
#pragma unroll
      for (int i = 0; i < 4; ++i)
#pragma unroll
        for (int r = 0; r < 4; ++r) {
          int m = m0 + wr + 16 * i + quad * 4 + r;
          out[(long)m * 1024 + n] = acc[c][i][r];
        }
    }
  }
}

extern "C" void kernel_launch(void* const* d_in, const int* in_sizes, int n_in,
                              void* d_out, int out_size, void* d_ws, size_t ws_size,
                              hipStream_t stream) {
  const float* x  = (const float*)d_in[0];
  const float* Wq = (const float*)d_in[1];
  const float* bq = (const float*)d_in[2];
  const float* Wk = (const float*)d_in[3];
  const float* bk = (const float*)d_in[4];
  const float* Wv = (const float*)d_in[5];
  const float* bv = (const float*)d_in[6];
  const float* Wo = (const float*)d_in[7];
  float* out = (float*)d_out;

  bf16* ws = (bf16*)d_ws;
  const long MB1 = 1 << 20;
  bf16* WqkvT = ws + 0 * MB1;    // [3072][1024]
  bf16* WoT   = ws + 3 * MB1;
  bf16* Q     = ws + 4 * MB1;    // [b][h][s][d]
  bf16* K_    = ws + 8 * MB1;    // [b][h][s][d]
  bf16* Vt    = ws + 12 * MB1;   // [b][h][d][s]
  bf16* O     = ws + 16 * MB1;   // [b][h][s][d]
  bf16* xb    = ws + 20 * MB1;

  // barrier counters + attn work queue live in d_out[0..15]; zero them.
  // (phase 3 overwrites these bytes with real output after the last barrier)
  hipMemsetAsync(d_out, 0, 64, stream);
  mha_fused<<<768, 256, 0, stream>>>(x, Wq, bq, Wk, bk, Wv, bv, Wo,
                                     WqkvT, WoT, Q, K_, Vt, O, xb,
                                     out, (unsigned*)d_out);
}